// Round 15
// baseline (848.456 us; speedup 1.0000x reference)
//
#include <hip/hip_runtime.h>
#include <hip/hip_bf16.h>

#define N_PKT 131072
#define KD 128
#define DM 256
#define HDIM 256
#define NCOMP 1024
#define ADIM 64

typedef __attribute__((ext_vector_type(8))) short v8s;
typedef __attribute__((ext_vector_type(4))) float v4f;

__device__ inline unsigned short f2bf(float f) {
  __hip_bfloat16 h = __float2bfloat16(f);
  return *reinterpret_cast<unsigned short*>(&h);
}

__device__ inline float bf2f(unsigned short u) {
  return __uint_as_float(((unsigned)u) << 16);
}

// exact tanh-GELU, 8-op form: x - x / (1 + exp2(x*(c1 + c2*x^2)))
__device__ inline float gelu_f(float x) {
  float x2 = x * x;
  float p = fmaf(x2, 0.10294540f, 2.30208889f);  // 2*0.79788456*log2e*(1, 0.044715)
  float e = __builtin_amdgcn_exp2f(x * p);
  float r = __builtin_amdgcn_rcpf(1.0f + e);
  return x - x * r;
}

// ---------------- one-shot prep ----------------
// Pack layout P[((nt*nKT+kt)*64+l)*8+j] = Wrow[kt*32+(l>>4)*8+j] col[nt*16+(l&15)]
//   Wcat (640x256 = [Wk; Wa; 0.1*Wr], nKT=20)   @ 0       (163840 shorts)
//   Wb0' (256x256, row k scaled by g_in[k])     @ 163840
//   Wb1' (256x256, row k scaled by g0[k])       @ 229376
//   Ww   (256x1024)                             @ 294912
//   Wq   (256x1024)                             @ 557056
//   Wad  (256x64)                               @ 819200  (ends 835584)
struct PrepParams {
  const float *Wk, *Wa, *Wr, *Wb0, *Wb1, *Ww, *Wq, *Wad;
  const float *bk, *ba, *br, *bb0, *bb1;
  const float *g_in, *b_in, *g0, *be0;
  unsigned short* P;
  float* bcomb; float* bb0adj; float* bb1adj;
};

__global__ void prep_kern(PrepParams pp) {
  const int tid = threadIdx.x;
  if (blockIdx.x >= 3264) {
    if (blockIdx.x == 3264) {
      pp.bcomb[tid] = pp.bk[tid] + pp.ba[tid] + 0.1f * pp.br[tid];
    } else {
      // bias adjust: bb0' = bb0 + b_in @ Wb0 ; bb1' = bb1 + beta0 @ Wb1
      const float* vsrc = (blockIdx.x == 3265) ? pp.b_in : pp.be0;
      const float* Wsrc = (blockIdx.x == 3265) ? pp.Wb0 : pp.Wb1;
      const float* badd = (blockIdx.x == 3265) ? pp.bb0 : pp.bb1;
      float* dst = (blockIdx.x == 3265) ? pp.bb0adj : pp.bb1adj;
      float s = badd[tid];
      #pragma unroll 8
      for (int k = 0; k < 256; ++k) s = fmaf(vsrc[k], Wsrc[(long)k * 256 + tid], s);
      dst[tid] = s;
    }
    return;
  }
  long gid = (long)blockIdx.x * 256 + tid;
  int K, Nc; long base; int seg;
  if      (gid < 163840) { K = 640; Nc = 256;  base = 0;      seg = 0; }
  else if (gid < 229376) { K = 256; Nc = 256;  base = 163840; seg = 1; }
  else if (gid < 294912) { K = 256; Nc = 256;  base = 229376; seg = 2; }
  else if (gid < 557056) { K = 256; Nc = 1024; base = 294912; seg = 3; }
  else if (gid < 819200) { K = 256; Nc = 1024; base = 557056; seg = 4; }
  else                   { K = 256; Nc = 64;   base = 819200; seg = 5; }
  long idx = gid - base;
  int j = (int)(idx & 7);
  int l = (int)((idx >> 3) & 63);
  long t = idx >> 9;
  int nKT = K >> 5;
  int kt = (int)(t % nKT), nt = (int)(t / nKT);
  int k = kt * 32 + (l >> 4) * 8 + j;
  int n = nt * 16 + (l & 15);
  float v;
  if (seg == 0) {
    if (k < 128)      v = pp.Wk[(long)k * 256 + n];
    else if (k < 384) v = pp.Wa[(long)(k - 128) * 256 + n];
    else              v = 0.1f * pp.Wr[(long)(k - 384) * 256 + n];
  } else if (seg == 1) v = pp.g_in[k] * pp.Wb0[(long)k * 256 + n];
  else if (seg == 2)   v = pp.g0[k] * pp.Wb1[(long)k * 256 + n];
  else if (seg == 3)   v = pp.Ww[(long)k * Nc + n];
  else if (seg == 4)   v = pp.Wq[(long)k * Nc + n];
  else                 v = pp.Wad[(long)k * Nc + n];
  pp.P[gid] = f2bf(v);
}

// ---------------- wave-local helpers (wave owns 16 rows) ----------------
// Stage 16 rows x COLS f32 (in-tile permuted) into tile rows [wrow0, wrow0+16).
template<int COLS>
__device__ inline void stage_rows_w(const float* __restrict__ src, long R0,
                                    const int* __restrict__ rows,
                                    unsigned short (&tile)[64][264], int wrow0, int lane) {
  constexpr int C4 = COLS / 4;
  #pragma unroll
  for (int j = 0; j < 16 * C4 / 64; ++j) {
    int idx = lane + j * 64;
    int r = wrow0 + idx / C4;
    int c4 = idx % C4;
    float4 v = *(reinterpret_cast<const float4*>(src + (R0 + rows[r]) * (long)COLS) + c4);
    unsigned long long pk = (unsigned long long)f2bf(v.x)
                          | ((unsigned long long)f2bf(v.y) << 16)
                          | ((unsigned long long)f2bf(v.z) << 32)
                          | ((unsigned long long)f2bf(v.w) << 48);
    *reinterpret_cast<unsigned long long*>(&tile[r][c4 * 4]) = pk;
  }
}

// acc[nt] += A(own 16 rows x 32*NKT) @ W-fragments over all 16 n-tiles.
template<int NKT, int KTOFF, int KSTRIDE>
__device__ inline void gemm_w(const unsigned short* __restrict__ Wp,
                              const unsigned short (&tile)[64][264],
                              int wrow0, int lane, v4f (&acc)[16]) {
  const int lr = lane & 15, lg = lane >> 4;
  #pragma unroll
  for (int kt = 0; kt < NKT; ++kt) {
    v8s a = *reinterpret_cast<const v8s*>(&tile[wrow0 + lr][kt * 32 + lg * 8]);
    #pragma unroll
    for (int nt = 0; nt < 16; ++nt) {
      v8s b = *reinterpret_cast<const v8s*>(
          Wp + (((long)nt * KSTRIDE + KTOFF + kt) * 64 + lane) * 8);
      acc[nt] = __builtin_amdgcn_mfma_f32_16x16x32_bf16(a, b, acc[nt], 0, 0, 0);
    }
  }
}

__device__ inline void init_acc_w(v4f (&acc)[16], const float* __restrict__ bias, int lr) {
  #pragma unroll
  for (int nt = 0; nt < 16; ++nt) {
    float bv = bias[nt * 16 + lr];
    acc[nt] = (v4f){bv, bv, bv, bv};
  }
}

// GELU(opt) -> row-wise LN (wave-local: 16-lane shfl reduce, NO barrier).
// AFFINE==false writes normalized z; AFFINE==true writes y = z*g+b.
template<bool GELU, bool AFFINE>
__device__ inline void ln_w(v4f (&acc)[16], int lane,
                            const float* __restrict__ gamma, const float* __restrict__ beta,
                            unsigned short (&tile)[64][264], int wrow0) {
  const int lr = lane & 15, lg = lane >> 4;
  if (GELU) {
    #pragma unroll
    for (int nt = 0; nt < 16; ++nt)
      #pragma unroll
      for (int r = 0; r < 4; ++r)
        acc[nt][r] = gelu_f(acc[nt][r]);
  }
  float s[4], q[4];
  #pragma unroll
  for (int r = 0; r < 4; ++r) {
    float t = 0.f, t2 = 0.f;
    #pragma unroll
    for (int nt = 0; nt < 16; ++nt) { float v = acc[nt][r]; t += v; t2 = fmaf(v, v, t2); }
    s[r] = t; q[r] = t2;
  }
  #pragma unroll
  for (int off = 1; off < 16; off <<= 1)
    #pragma unroll
    for (int r = 0; r < 4; ++r) {
      s[r] += __shfl_xor(s[r], off);
      q[r] += __shfl_xor(q[r], off);
    }
  float mean[4], rstd[4];
  #pragma unroll
  for (int r = 0; r < 4; ++r) {
    mean[r] = s[r] * (1.0f / 256.0f);
    float var = q[r] * (1.0f / 256.0f) - mean[r] * mean[r];
    rstd[r] = rsqrtf(var + 1e-5f);
  }
  #pragma unroll
  for (int nt = 0; nt < 16; ++nt) {
    float gv = 1.f, bv = 0.f;
    if (AFFINE) { gv = gamma[nt * 16 + lr]; bv = beta[nt * 16 + lr]; }
    #pragma unroll
    for (int r = 0; r < 4; ++r) {
      float z = (acc[nt][r] - mean[r]) * rstd[r];
      float y = AFFINE ? fmaf(z, gv, bv) : z;
      tile[wrow0 + lg * 4 + r][nt * 16 + lr] = f2bf(y);
    }
  }
  // no barrier: next backbone layer reads only this wave's own rows
}

// ---------------- fused kernel: in-tile sort + barrier-free backbone + heads ----
struct MegaParams {
  const float* key; const float* aux; const float* res; const int* role;
  const unsigned short* pWcat; const unsigned short* pWb0; const unsigned short* pWb1;
  const unsigned short* pWad; const unsigned short* pWw; const unsigned short* pWq;
  const float* bcomb; const float* bb0adj; const float* bb1adj;
  const float* g1; const float* be1; const float* bad;
  const float* bw; const float* bq;
  float* out_logits; float* out_h; float* out_aux;
};

__global__ __launch_bounds__(256, 3) void mega_kern(MegaParams p) {
  __shared__ alignas(16) unsigned short tile[64][264];
  __shared__ alignas(16) float stage[4][16][68];   // also aliased as [64][68] for aux
  __shared__ int rows[64];
  __shared__ int nwS;

  const int tid = threadIdx.x;
  const int lane = tid & 63;
  const int wave = tid >> 6;
  const int lr = lane & 15;
  const int lg = lane >> 4;
  const long R0 = (long)blockIdx.x * 64;
  const int wrow0 = wave * 16;

  // ---- in-tile role sort: writers to slots [0, nw), others [nw, 64) ----
  if (tid < 64) {
    int w = (p.role[R0 + tid] == 0) ? 1 : 0;
    unsigned long long mw = __ballot(w != 0);
    unsigned long long below = (tid == 0) ? 0ull : (~0ull >> (64 - tid));
    int nwv = __popcll(mw);
    int pos = w ? __popcll(mw & below) : nwv + __popcll((~mw) & below);
    rows[pos] = tid;
    if (tid == 0) nwS = nwv;
  }
  __syncthreads();
  const int nw = nwS;

  v4f acc[16];

  // ---- backbone: fully wave-local, ZERO block barriers ----
  // stage 1: [key|aux|res] @ Wcat (K=640, nKT=20)
  init_acc_w(acc, p.bcomb, lr);
  stage_rows_w<KD>(p.key, R0, rows, tile, wrow0, lane);
  gemm_w<4, 0, 20>(p.pWcat, tile, wrow0, lane, acc);
  stage_rows_w<DM>(p.aux, R0, rows, tile, wrow0, lane);
  gemm_w<8, 4, 20>(p.pWcat, tile, wrow0, lane, acc);
  stage_rows_w<DM>(p.res, R0, rows, tile, wrow0, lane);
  gemm_w<8, 12, 20>(p.pWcat, tile, wrow0, lane, acc);
  ln_w<false, false>(acc, lane, nullptr, nullptr, tile, wrow0);

  // layer 0 (g_in folded into pWb0, b_in folded into bb0adj)
  init_acc_w(acc, p.bb0adj, lr);
  gemm_w<8, 0, 8>(p.pWb0, tile, wrow0, lane, acc);
  ln_w<true, false>(acc, lane, nullptr, nullptr, tile, wrow0);

  // layer 1 (g0 folded into pWb1; last LN keeps affine)
  init_acc_w(acc, p.bb1adj, lr);
  gemm_w<8, 0, 8>(p.pWb1, tile, wrow0, lane, acc);
  ln_w<true, true>(acc, lane, p.g1, p.be1, tile, wrow0);

  // ---- coalesced h dump: own 16 rows, full 1KB per wave-instruction ----
  #pragma unroll
  for (int i = 0; i < 16; ++i) {
    int slot = wrow0 + i;
    unsigned long long t4 = *reinterpret_cast<const unsigned long long*>(&tile[slot][lane * 4]);
    v4f v;
    v[0] = bf2f((unsigned short)(t4 & 0xffff));
    v[1] = bf2f((unsigned short)((t4 >> 16) & 0xffff));
    v[2] = bf2f((unsigned short)((t4 >> 32) & 0xffff));
    v[3] = bf2f((unsigned short)((t4 >> 48) & 0xffff));
    *reinterpret_cast<v4f*>(p.out_h + (R0 + rows[slot]) * HDIM + lane * 4) = v;
  }

  __syncthreads();   // tile complete: heads read cross-wave rows

  // ---- address head: col-slice per wave, stage [64][68], full-row stores ----
  {
    float (*astage)[68] = reinterpret_cast<float(*)[68]>(&stage[0][0][0]);
    v4f a4[4];
    float bv = p.bad[wave * 16 + lr];
    #pragma unroll
    for (int m = 0; m < 4; ++m) a4[m] = (v4f){bv, bv, bv, bv};
    #pragma unroll
    for (int kt = 0; kt < 8; ++kt) {
      v8s b = *reinterpret_cast<const v8s*>(p.pWad + (((long)wave * 8 + kt) * 64 + lane) * 8);
      #pragma unroll
      for (int m = 0; m < 4; ++m) {
        v8s am = *reinterpret_cast<const v8s*>(&tile[m * 16 + lr][kt * 32 + lg * 8]);
        a4[m] = __builtin_amdgcn_mfma_f32_16x16x32_bf16(am, b, a4[m], 0, 0, 0);
      }
    }
    #pragma unroll
    for (int m = 0; m < 4; ++m)
      #pragma unroll
      for (int r = 0; r < 4; ++r)
        astage[m * 16 + lg * 4 + r][wave * 16 + lr] = a4[m][r];
    __syncthreads();
    #pragma unroll
    for (int k = 0; k < 4; ++k) {
      int idx = tid + k * 256;
      int slot = idx >> 4;
      int c4 = idx & 15;
      v4f v = *reinterpret_cast<const v4f*>(&astage[slot][c4 * 4]);
      *reinterpret_cast<v4f*>(p.out_aux + (R0 + rows[slot]) * ADIM + c4 * 4) = v;
    }
    __syncthreads();   // aux reads of stage done before role heads reuse it
  }

  // ---- role heads: sorted tile => per-m-subtile head skip; full-line stores ----
  const int rr = lane >> 3;   // 0..7
  const int ce = lane & 7;    // 0..7
  #pragma unroll 1
  for (int hsel = 0; hsel < 2; ++hsel) {
    const unsigned short* Wp = hsel == 0 ? p.pWw : p.pWq;
    const float* bias = hsel == 0 ? p.bw : p.bq;
    // m-subtile [m*16, m*16+16) needed for this head? (block-uniform => no divergence)
    bool needm[4];
    #pragma unroll
    for (int m = 0; m < 4; ++m)
      needm[m] = (hsel == 0) ? (m * 16 < nw) : ((m + 1) * 16 > nw);
    #pragma unroll 1
    for (int c = 0; c < 4; ++c) {
      const int nth = wave * 16 + c * 4;
      v4f hacc[4][4];
      #pragma unroll
      for (int nf = 0; nf < 4; ++nf) {
        v4f bv = *reinterpret_cast<const v4f*>(bias + (nth + nf) * 16 + lg * 4);
        #pragma unroll
        for (int m = 0; m < 4; ++m) hacc[m][nf] = bv;
      }
      v8s wcur[4], wnxt[4];
      #pragma unroll
      for (int nf = 0; nf < 4; ++nf)
        wcur[nf] = *reinterpret_cast<const v8s*>(Wp + (((long)(nth + nf) * 8 + 0) * 64 + lane) * 8);
      #pragma unroll
      for (int kt = 0; kt < 8; ++kt) {
        if (kt < 7) {
          #pragma unroll
          for (int nf = 0; nf < 4; ++nf)
            wnxt[nf] = *reinterpret_cast<const v8s*>(Wp + (((long)(nth + nf) * 8 + kt + 1) * 64 + lane) * 8);
        }
        #pragma unroll
        for (int m = 0; m < 4; ++m) {
          if (!needm[m]) continue;
          v8s a = *reinterpret_cast<const v8s*>(&tile[m * 16 + lr][kt * 32 + lg * 8]);
          #pragma unroll
          for (int nf = 0; nf < 4; ++nf)
            hacc[m][nf] = __builtin_amdgcn_mfma_f32_16x16x32_bf16(wcur[nf], a, hacc[m][nf], 0, 0, 0);
        }
        if (kt < 7) {
          #pragma unroll
          for (int nf = 0; nf < 4; ++nf) wcur[nf] = wnxt[nf];
        }
      }
      // epilogue: per-wave LDS transpose -> 128B-aligned full-line stores
      #pragma unroll
      for (int m = 0; m < 4; ++m) {
        if (!needm[m]) continue;
        #pragma unroll
        for (int nf = 0; nf < 4; ++nf)
          *reinterpret_cast<v4f*>(&stage[wave][lr][nf * 16 + lg * 4]) = hacc[m][nf];
        __builtin_amdgcn_sched_barrier(0);
        #pragma unroll
        for (int rh = 0; rh < 2; ++rh) {
          int slot = m * 16 + rh * 8 + rr;
          bool doit = (hsel == 0) ? (slot < nw) : (slot >= nw);
          int ridx = rows[slot];
          #pragma unroll
          for (int ch = 0; ch < 2; ++ch) {
            v4f v = *reinterpret_cast<const v4f*>(&stage[wave][rh * 8 + rr][ch * 32 + ce * 4]);
            if (doit)
              *reinterpret_cast<v4f*>(p.out_logits + (R0 + ridx) * NCOMP
                                      + nth * 16 + ch * 32 + ce * 4) = v;
          }
        }
        __builtin_amdgcn_sched_barrier(0);
      }
    }
  }
}

extern "C" void kernel_launch(void* const* d_in, const int* in_sizes, int n_in,
                              void* d_out, int out_size, void* d_ws, size_t ws_size,
                              hipStream_t stream) {
  const float* key  = (const float*)d_in[0];
  const float* aux  = (const float*)d_in[1];
  const float* res  = (const float*)d_in[2];
  const int*   role = (const int*)d_in[3];
  const float* Wk = (const float*)d_in[4];   const float* bk = (const float*)d_in[5];
  const float* Wa = (const float*)d_in[6];   const float* ba = (const float*)d_in[7];
  const float* Wr = (const float*)d_in[8];   const float* br = (const float*)d_in[9];
  const float* g_in = (const float*)d_in[10]; const float* b_in = (const float*)d_in[11];
  const float* Wb0 = (const float*)d_in[12]; const float* bb0 = (const float*)d_in[13];
  const float* g0 = (const float*)d_in[14];  const float* be0 = (const float*)d_in[15];
  const float* Wb1 = (const float*)d_in[16]; const float* bb1 = (const float*)d_in[17];
  const float* g1 = (const float*)d_in[18];  const float* be1 = (const float*)d_in[19];
  const float* Ww = (const float*)d_in[20];  const float* bw = (const float*)d_in[21];
  const float* Wq = (const float*)d_in[22];  const float* bq = (const float*)d_in[23];
  const float* Wad = (const float*)d_in[24]; const float* bad = (const float*)d_in[25];

  unsigned short* wsp = (unsigned short*)d_ws;
  unsigned short* pWcat = wsp + 0;
  unsigned short* pWb0  = wsp + 163840;
  unsigned short* pWb1  = wsp + 229376;
  unsigned short* pWw   = wsp + 294912;
  unsigned short* pWq   = wsp + 557056;
  unsigned short* pWad  = wsp + 819200;
  char* wsb = (char*)d_ws;
  float* bcomb  = (float*)(wsb + 1671168);
  float* bb0adj = (float*)(wsb + 1672192);
  float* bb1adj = (float*)(wsb + 1673216);

  PrepParams pp;
  pp.Wk = Wk; pp.Wa = Wa; pp.Wr = Wr; pp.Wb0 = Wb0; pp.Wb1 = Wb1;
  pp.Ww = Ww; pp.Wq = Wq; pp.Wad = Wad;
  pp.bk = bk; pp.ba = ba; pp.br = br; pp.bb0 = bb0; pp.bb1 = bb1;
  pp.g_in = g_in; pp.b_in = b_in; pp.g0 = g0; pp.be0 = be0;
  pp.P = wsp; pp.bcomb = bcomb; pp.bb0adj = bb0adj; pp.bb1adj = bb1adj;
  prep_kern<<<3267, 256, 0, stream>>>(pp);

  float* out = (float*)d_out;
  MegaParams P;
  P.key = key; P.aux = aux; P.res = res; P.role = role;
  P.pWcat = pWcat; P.pWb0 = pWb0; P.pWb1 = pWb1; P.pWad = pWad;
  P.pWw = pWw; P.pWq = pWq;
  P.bcomb = bcomb; P.bb0adj = bb0adj; P.bb1adj = bb1adj;
  P.g1 = g1; P.be1 = be1; P.bad = bad; P.bw = bw; P.bq = bq;
  P.out_logits = out;
  P.out_h = out + (size_t)N_PKT * NCOMP;
  P.out_aux = out + (size_t)N_PKT * (NCOMP + HDIM);
  mega_kern<<<N_PKT / 64, 256, 0, stream>>>(P);
}

// Round 16
// 433.610 us; speedup vs baseline: 1.9567x; 1.9567x over previous
//
#include <hip/hip_runtime.h>
#include <hip/hip_bf16.h>

#define N_PKT 131072
#define KD 128
#define DM 256
#define HDIM 256
#define NCOMP 1024
#define ADIM 64

typedef __attribute__((ext_vector_type(8))) short v8s;
typedef __attribute__((ext_vector_type(4))) float v4f;

__device__ inline unsigned short f2bf(float f) {
  __hip_bfloat16 h = __float2bfloat16(f);
  return *reinterpret_cast<unsigned short*>(&h);
}

__device__ inline float bf2f(unsigned short u) {
  return __uint_as_float(((unsigned)u) << 16);
}

// exact tanh-GELU, 8-op form: x - x / (1 + exp2(x*(c1 + c2*x^2)))
__device__ inline float gelu_f(float x) {
  float x2 = x * x;
  float p = fmaf(x2, 0.10294540f, 2.30208889f);  // 2*0.79788456*log2e*(1, 0.044715)
  float e = __builtin_amdgcn_exp2f(x * p);
  float r = __builtin_amdgcn_rcpf(1.0f + e);
  return x - x * r;
}

__device__ inline unsigned long long pack4(float4 v) {
  return (unsigned long long)f2bf(v.x)
       | ((unsigned long long)f2bf(v.y) << 16)
       | ((unsigned long long)f2bf(v.z) << 32)
       | ((unsigned long long)f2bf(v.w) << 48);
}

// ---------------- one-shot prep ----------------
// Pack layout P[((nt*nKT+kt)*64+l)*8+j] = Wrow[kt*32+(l>>4)*8+j] col[nt*16+(l&15)]
//   Wcat (640x256 = [Wk; Wa; 0.1*Wr], nKT=20)   @ 0       (163840 shorts)
//   Wb0' (256x256, row k scaled by g_in[k])     @ 163840
//   Wb1' (256x256, row k scaled by g0[k])       @ 229376
//   Ww   (256x1024)                             @ 294912
//   Wq   (256x1024)                             @ 557056
//   Wad  (256x64)                               @ 819200  (ends 835584)
struct PrepParams {
  const float *Wk, *Wa, *Wr, *Wb0, *Wb1, *Ww, *Wq, *Wad;
  const float *bk, *ba, *br, *bb0, *bb1;
  const float *g_in, *b_in, *g0, *be0;
  unsigned short* P;
  float* bcomb; float* bb0adj; float* bb1adj;
};

__global__ void prep_kern(PrepParams pp) {
  const int tid = threadIdx.x;
  if (blockIdx.x >= 3264) {
    if (blockIdx.x == 3264) {
      pp.bcomb[tid] = pp.bk[tid] + pp.ba[tid] + 0.1f * pp.br[tid];
    } else {
      // bias adjust: bb0' = bb0 + b_in @ Wb0 ; bb1' = bb1 + beta0 @ Wb1
      const float* vsrc = (blockIdx.x == 3265) ? pp.b_in : pp.be0;
      const float* Wsrc = (blockIdx.x == 3265) ? pp.Wb0 : pp.Wb1;
      const float* badd = (blockIdx.x == 3265) ? pp.bb0 : pp.bb1;
      float* dst = (blockIdx.x == 3265) ? pp.bb0adj : pp.bb1adj;
      float s = badd[tid];
      #pragma unroll 8
      for (int k = 0; k < 256; ++k) s = fmaf(vsrc[k], Wsrc[(long)k * 256 + tid], s);
      dst[tid] = s;
    }
    return;
  }
  long gid = (long)blockIdx.x * 256 + tid;
  int K, Nc; long base; int seg;
  if      (gid < 163840) { K = 640; Nc = 256;  base = 0;      seg = 0; }
  else if (gid < 229376) { K = 256; Nc = 256;  base = 163840; seg = 1; }
  else if (gid < 294912) { K = 256; Nc = 256;  base = 229376; seg = 2; }
  else if (gid < 557056) { K = 256; Nc = 1024; base = 294912; seg = 3; }
  else if (gid < 819200) { K = 256; Nc = 1024; base = 557056; seg = 4; }
  else                   { K = 256; Nc = 64;   base = 819200; seg = 5; }
  long idx = gid - base;
  int j = (int)(idx & 7);
  int l = (int)((idx >> 3) & 63);
  long t = idx >> 9;
  int nKT = K >> 5;
  int kt = (int)(t % nKT), nt = (int)(t / nKT);
  int k = kt * 32 + (l >> 4) * 8 + j;
  int n = nt * 16 + (l & 15);
  float v;
  if (seg == 0) {
    if (k < 128)      v = pp.Wk[(long)k * 256 + n];
    else if (k < 384) v = pp.Wa[(long)(k - 128) * 256 + n];
    else              v = 0.1f * pp.Wr[(long)(k - 384) * 256 + n];
  } else if (seg == 1) v = pp.g_in[k] * pp.Wb0[(long)k * 256 + n];
  else if (seg == 2)   v = pp.g0[k] * pp.Wb1[(long)k * 256 + n];
  else if (seg == 3)   v = pp.Ww[(long)k * Nc + n];
  else if (seg == 4)   v = pp.Wq[(long)k * Nc + n];
  else                 v = pp.Wad[(long)k * Nc + n];
  pp.P[gid] = f2bf(v);
}

// ---------------- shared helpers ----------------
// acc += tile(64 x 32*NKT) @ W-fragments. W packed with K-tile stride KSTRIDE,
// starting at K-tile KTOFF. Wave's n-tile base nt0.
template<int NKT, int KTOFF, int KSTRIDE>
__device__ inline void gemm_acc(const unsigned short* __restrict__ Wp, int nt0,
                                const unsigned short (&tile)[64][264], int lane,
                                v4f (&acc)[4][4]) {
  const int lr = lane & 15, lg = lane >> 4;
  #pragma unroll
  for (int kt = 0; kt < NKT; ++kt) {
    v8s b[4];
    #pragma unroll
    for (int nf = 0; nf < 4; ++nf)
      b[nf] = *reinterpret_cast<const v8s*>(
          Wp + (((long)(nt0 + nf) * KSTRIDE + KTOFF + kt) * 64 + lane) * 8);
    #pragma unroll
    for (int m = 0; m < 4; ++m) {
      v8s a = *reinterpret_cast<const v8s*>(&tile[m * 16 + lr][kt * 32 + lg * 8]);
      #pragma unroll
      for (int nf = 0; nf < 4; ++nf)
        acc[m][nf] = __builtin_amdgcn_mfma_f32_16x16x32_bf16(a, b[nf], acc[m][nf], 0, 0, 0);
    }
  }
}

__device__ inline void init_acc(v4f (&acc)[4][4], const float* __restrict__ bias,
                                int colbase, int lr) {
  float bv[4];
  #pragma unroll
  for (int nf = 0; nf < 4; ++nf) bv[nf] = bias[colbase + nf * 16 + lr];
  #pragma unroll
  for (int m = 0; m < 4; ++m)
    #pragma unroll
    for (int nf = 0; nf < 4; ++nf)
      acc[m][nf] = (v4f){bv[nf], bv[nf], bv[nf], bv[nf]};
}

// GELU(opt) -> LN over 256 cols. AFFINE==false: write normalized z (affine folded
// into next weights). AFFINE==true: y = z*g+b written to tile.
template<bool GELU, bool AFFINE>
__device__ inline void ln_stage(v4f (&acc)[4][4], int wave, int lane,
                                const float* __restrict__ gamma, const float* __restrict__ beta,
                                unsigned short (&tile)[64][264], float (&stats)[2][4][64]) {
  const int lr = lane & 15, lg = lane >> 4;
  if (GELU) {
    #pragma unroll
    for (int m = 0; m < 4; ++m)
      #pragma unroll
      for (int nf = 0; nf < 4; ++nf)
        #pragma unroll
        for (int r = 0; r < 4; ++r)
          acc[m][nf][r] = gelu_f(acc[m][nf][r]);
  }
  float s[4][4], q[4][4];
  #pragma unroll
  for (int m = 0; m < 4; ++m)
    #pragma unroll
    for (int r = 0; r < 4; ++r) {
      float t = 0.f, t2 = 0.f;
      #pragma unroll
      for (int nf = 0; nf < 4; ++nf) { float v = acc[m][nf][r]; t += v; t2 = fmaf(v, v, t2); }
      s[m][r] = t; q[m][r] = t2;
    }
  #pragma unroll
  for (int off = 1; off < 16; off <<= 1)
    #pragma unroll
    for (int m = 0; m < 4; ++m)
      #pragma unroll
      for (int r = 0; r < 4; ++r) {
        s[m][r] += __shfl_xor(s[m][r], off);
        q[m][r] += __shfl_xor(q[m][r], off);
      }
  if (lr == 0) {
    #pragma unroll
    for (int m = 0; m < 4; ++m)
      #pragma unroll
      for (int r = 0; r < 4; ++r) {
        int row = m * 16 + lg * 4 + r;
        stats[0][wave][row] = s[m][r];
        stats[1][wave][row] = q[m][r];
      }
  }
  __syncthreads();
  float gv[4], bv[4];
  if (AFFINE) {
    #pragma unroll
    for (int nf = 0; nf < 4; ++nf) {
      int c = wave * 64 + nf * 16 + lr;
      gv[nf] = gamma[c]; bv[nf] = beta[c];
    }
  }
  #pragma unroll
  for (int m = 0; m < 4; ++m)
    #pragma unroll
    for (int r = 0; r < 4; ++r) {
      int row = m * 16 + lg * 4 + r;
      float S = stats[0][0][row] + stats[0][1][row] + stats[0][2][row] + stats[0][3][row];
      float Q = stats[1][0][row] + stats[1][1][row] + stats[1][2][row] + stats[1][3][row];
      float mean = S * (1.0f / 256.0f);
      float var  = Q * (1.0f / 256.0f) - mean * mean;
      float rstd = rsqrtf(var + 1e-5f);
      #pragma unroll
      for (int nf = 0; nf < 4; ++nf) {
        int c = wave * 64 + nf * 16 + lr;
        float z = (acc[m][nf][r] - mean) * rstd;
        float y = AFFINE ? fmaf(z, gv[nf], bv[nf]) : z;
        tile[row][c] = f2bf(y);
      }
    }
  __syncthreads();
}

// ---------------- fused kernel: in-tile role sort + backbone + heads ----------------
struct MegaParams {
  const float* key; const float* aux; const float* res; const int* role;
  const unsigned short* pWcat; const unsigned short* pWb0; const unsigned short* pWb1;
  const unsigned short* pWad; const unsigned short* pWw; const unsigned short* pWq;
  const float* bcomb; const float* bb0adj; const float* bb1adj;
  const float* g1; const float* be1; const float* bad;
  const float* bw; const float* bq;
  float* out_logits; float* out_h; float* out_aux;
};

__global__ __launch_bounds__(256, 3) void mega_kern(MegaParams p) {
  __shared__ alignas(16) unsigned short tile[64][264];
  __shared__ float stats[2][4][64];
  __shared__ alignas(16) float stage[4][16][68];   // also aliased as [64][68] for aux
  __shared__ int rows[64];
  __shared__ int nwS;

  const int tid = threadIdx.x;
  const int lane = tid & 63;
  const int wave = tid >> 6;
  const int lr = lane & 15;
  const int lg = lane >> 4;
  const long R0 = (long)blockIdx.x * 64;
  const int nt0 = wave * 4;

  // ---- in-tile role sort: writers to slots [0, nw), others [nw, 64) ----
  if (tid < 64) {
    int w = (p.role[R0 + tid] == 0) ? 1 : 0;
    unsigned long long mw = __ballot(w != 0);
    unsigned long long below = (tid == 0) ? 0ull : (~0ull >> (64 - tid));
    int nw = __popcll(mw);
    int pos = w ? __popcll(mw & below) : nw + __popcll((~mw) & below);
    rows[pos] = tid;
    if (tid == 0) nwS = nw;
  }
  __syncthreads();
  const int nw = nwS;

  v4f acc[4][4];

  // ---- stage 1 (T14 issue-early pipeline): [key|aux|res] @ Wcat ----
  // key load indices: idx = tid + i*256, r = idx>>5, c4 = idx&31  (i<8)
  // aux/res:          idx = tid + i*256, r = idx>>6, c4 = idx&63  (i<16)
  init_acc(acc, p.bcomb, wave * 64, lr);
  float4 pre[16];
  #pragma unroll
  for (int i = 0; i < 8; ++i) {
    int idx = tid + i * 256;
    pre[i] = *(reinterpret_cast<const float4*>(p.key + (R0 + rows[idx >> 5]) * (long)KD) + (idx & 31));
  }
  #pragma unroll
  for (int i = 0; i < 8; ++i) {
    int idx = tid + i * 256;
    *reinterpret_cast<unsigned long long*>(&tile[idx >> 5][(idx & 31) * 4]) = pack4(pre[i]);
  }
  __syncthreads();
  // issue aux loads BEFORE gemm(key): latency hides under the 64 MFMAs
  #pragma unroll
  for (int i = 0; i < 16; ++i) {
    int idx = tid + i * 256;
    pre[i] = *(reinterpret_cast<const float4*>(p.aux + (R0 + rows[idx >> 6]) * (long)DM) + (idx & 63));
  }
  gemm_acc<4, 0, 20>(p.pWcat, nt0, tile, lane, acc);
  __syncthreads();
  #pragma unroll
  for (int i = 0; i < 16; ++i) {
    int idx = tid + i * 256;
    *reinterpret_cast<unsigned long long*>(&tile[idx >> 6][(idx & 63) * 4]) = pack4(pre[i]);
  }
  __syncthreads();
  // issue res loads BEFORE gemm(aux)
  #pragma unroll
  for (int i = 0; i < 16; ++i) {
    int idx = tid + i * 256;
    pre[i] = *(reinterpret_cast<const float4*>(p.res + (R0 + rows[idx >> 6]) * (long)DM) + (idx & 63));
  }
  gemm_acc<8, 4, 20>(p.pWcat, nt0, tile, lane, acc);
  __syncthreads();
  #pragma unroll
  for (int i = 0; i < 16; ++i) {
    int idx = tid + i * 256;
    *reinterpret_cast<unsigned long long*>(&tile[idx >> 6][(idx & 63) * 4]) = pack4(pre[i]);
  }
  __syncthreads();
  gemm_acc<8, 12, 20>(p.pWcat, nt0, tile, lane, acc);
  ln_stage<false, false>(acc, wave, lane, nullptr, nullptr, tile, stats);

  // ---- backbone layer 0 (g_in folded into pWb0, b_in folded into bb0adj) ----
  init_acc(acc, p.bb0adj, wave * 64, lr);
  gemm_acc<8, 0, 8>(p.pWb0, nt0, tile, lane, acc);
  ln_stage<true, false>(acc, wave, lane, nullptr, nullptr, tile, stats);

  // ---- backbone layer 1 (g0 folded into pWb1; last LN keeps affine) ----
  init_acc(acc, p.bb1adj, wave * 64, lr);
  gemm_acc<8, 0, 8>(p.pWb1, nt0, tile, lane, acc);
  ln_stage<true, true>(acc, wave, lane, p.g1, p.be1, tile, stats);

  // ---- coalesced h dump: full 1KB row per wave-instruction (in-tile scatter) ----
  #pragma unroll
  for (int i = 0; i < 16; ++i) {
    int slot = wave * 16 + i;
    unsigned long long t4 = *reinterpret_cast<const unsigned long long*>(&tile[slot][lane * 4]);
    v4f v;
    v[0] = bf2f((unsigned short)(t4 & 0xffff));
    v[1] = bf2f((unsigned short)((t4 >> 16) & 0xffff));
    v[2] = bf2f((unsigned short)((t4 >> 32) & 0xffff));
    v[3] = bf2f((unsigned short)((t4 >> 48) & 0xffff));
    *reinterpret_cast<v4f*>(p.out_h + (R0 + rows[slot]) * HDIM + lane * 4) = v;
  }

  // ---- address head: compute, stage into LDS ([64][68] alias), full-row stores ----
  {
    float (*astage)[68] = reinterpret_cast<float(*)[68]>(&stage[0][0][0]);
    v4f a4[4];
    float bv = p.bad[wave * 16 + lr];
    #pragma unroll
    for (int m = 0; m < 4; ++m) a4[m] = (v4f){bv, bv, bv, bv};
    #pragma unroll
    for (int kt = 0; kt < 8; ++kt) {
      v8s b = *reinterpret_cast<const v8s*>(p.pWad + (((long)wave * 8 + kt) * 64 + lane) * 8);
      #pragma unroll
      for (int m = 0; m < 4; ++m) {
        v8s am = *reinterpret_cast<const v8s*>(&tile[m * 16 + lr][kt * 32 + lg * 8]);
        a4[m] = __builtin_amdgcn_mfma_f32_16x16x32_bf16(am, b, a4[m], 0, 0, 0);
      }
    }
    #pragma unroll
    for (int m = 0; m < 4; ++m)
      #pragma unroll
      for (int r = 0; r < 4; ++r)
        astage[m * 16 + lg * 4 + r][wave * 16 + lr] = a4[m][r];
    __syncthreads();
    #pragma unroll
    for (int k = 0; k < 4; ++k) {
      int idx = tid + k * 256;
      int slot = idx >> 4;
      int c4 = idx & 15;
      v4f v = *reinterpret_cast<const v4f*>(&astage[slot][c4 * 4]);
      *reinterpret_cast<v4f*>(p.out_aux + (R0 + rows[slot]) * ADIM + c4 * 4) = v;
    }
    __syncthreads();   // aux reads of stage done before role heads reuse it
  }

  // ---- role heads: sorted tile => per-m-subtile head skip; full-line stores ----
  const int rr = lane >> 3;   // 0..7
  const int ce = lane & 7;    // 0..7
  #pragma unroll 1
  for (int hsel = 0; hsel < 2; ++hsel) {
    const unsigned short* Wp = hsel == 0 ? p.pWw : p.pWq;
    const float* bias = hsel == 0 ? p.bw : p.bq;
    // m-subtile [m*16, m*16+16) needed for this head? (block-uniform => no divergence)
    bool needm[4];
    #pragma unroll
    for (int m = 0; m < 4; ++m)
      needm[m] = (hsel == 0) ? (m * 16 < nw) : ((m + 1) * 16 > nw);
    #pragma unroll 1
    for (int c = 0; c < 4; ++c) {
      const int nth = wave * 16 + c * 4;
      v4f hacc[4][4];
      #pragma unroll
      for (int nf = 0; nf < 4; ++nf) {
        v4f bv = *reinterpret_cast<const v4f*>(bias + (nth + nf) * 16 + lg * 4);
        #pragma unroll
        for (int m = 0; m < 4; ++m) hacc[m][nf] = bv;
      }
      v8s wcur[4], wnxt[4];
      #pragma unroll
      for (int nf = 0; nf < 4; ++nf)
        wcur[nf] = *reinterpret_cast<const v8s*>(Wp + (((long)(nth + nf) * 8 + 0) * 64 + lane) * 8);
      #pragma unroll
      for (int kt = 0; kt < 8; ++kt) {
        if (kt < 7) {
          #pragma unroll
          for (int nf = 0; nf < 4; ++nf)
            wnxt[nf] = *reinterpret_cast<const v8s*>(Wp + (((long)(nth + nf) * 8 + kt + 1) * 64 + lane) * 8);
        }
        #pragma unroll
        for (int m = 0; m < 4; ++m) {
          if (!needm[m]) continue;
          v8s a = *reinterpret_cast<const v8s*>(&tile[m * 16 + lr][kt * 32 + lg * 8]);
          #pragma unroll
          for (int nf = 0; nf < 4; ++nf)
            hacc[m][nf] = __builtin_amdgcn_mfma_f32_16x16x32_bf16(wcur[nf], a, hacc[m][nf], 0, 0, 0);
        }
        if (kt < 7) {
          #pragma unroll
          for (int nf = 0; nf < 4; ++nf) wcur[nf] = wnxt[nf];
        }
      }
      // epilogue: per-wave LDS transpose -> 128B-aligned full-line stores
      #pragma unroll
      for (int m = 0; m < 4; ++m) {
        if (!needm[m]) continue;
        #pragma unroll
        for (int nf = 0; nf < 4; ++nf)
          *reinterpret_cast<v4f*>(&stage[wave][lr][nf * 16 + lg * 4]) = hacc[m][nf];
        __builtin_amdgcn_sched_barrier(0);
        #pragma unroll
        for (int rh = 0; rh < 2; ++rh) {
          int slot = m * 16 + rh * 8 + rr;
          bool doit = (hsel == 0) ? (slot < nw) : (slot >= nw);
          int ridx = rows[slot];
          #pragma unroll
          for (int ch = 0; ch < 2; ++ch) {
            v4f v = *reinterpret_cast<const v4f*>(&stage[wave][rh * 8 + rr][ch * 32 + ce * 4]);
            if (doit)
              *reinterpret_cast<v4f*>(p.out_logits + (R0 + ridx) * NCOMP
                                      + nth * 16 + ch * 32 + ce * 4) = v;
          }
        }
        __builtin_amdgcn_sched_barrier(0);
      }
    }
  }
}

extern "C" void kernel_launch(void* const* d_in, const int* in_sizes, int n_in,
                              void* d_out, int out_size, void* d_ws, size_t ws_size,
                              hipStream_t stream) {
  const float* key  = (const float*)d_in[0];
  const float* aux  = (const float*)d_in[1];
  const float* res  = (const float*)d_in[2];
  const int*   role = (const int*)d_in[3];
  const float* Wk = (const float*)d_in[4];   const float* bk = (const float*)d_in[5];
  const float* Wa = (const float*)d_in[6];   const float* ba = (const float*)d_in[7];
  const float* Wr = (const float*)d_in[8];   const float* br = (const float*)d_in[9];
  const float* g_in = (const float*)d_in[10]; const float* b_in = (const float*)d_in[11];
  const float* Wb0 = (const float*)d_in[12]; const float* bb0 = (const float*)d_in[13];
  const float* g0 = (const float*)d_in[14];  const float* be0 = (const float*)d_in[15];
  const float* Wb1 = (const float*)d_in[16]; const float* bb1 = (const float*)d_in[17];
  const float* g1 = (const float*)d_in[18];  const float* be1 = (const float*)d_in[19];
  const float* Ww = (const float*)d_in[20];  const float* bw = (const float*)d_in[21];
  const float* Wq = (const float*)d_in[22];  const float* bq = (const float*)d_in[23];
  const float* Wad = (const float*)d_in[24]; const float* bad = (const float*)d_in[25];

  unsigned short* wsp = (unsigned short*)d_ws;
  unsigned short* pWcat = wsp + 0;
  unsigned short* pWb0  = wsp + 163840;
  unsigned short* pWb1  = wsp + 229376;
  unsigned short* pWw   = wsp + 294912;
  unsigned short* pWq   = wsp + 557056;
  unsigned short* pWad  = wsp + 819200;
  char* wsb = (char*)d_ws;
  float* bcomb  = (float*)(wsb + 1671168);
  float* bb0adj = (float*)(wsb + 1672192);
  float* bb1adj = (float*)(wsb + 1673216);

  PrepParams pp;
  pp.Wk = Wk; pp.Wa = Wa; pp.Wr = Wr; pp.Wb0 = Wb0; pp.Wb1 = Wb1;
  pp.Ww = Ww; pp.Wq = Wq; pp.Wad = Wad;
  pp.bk = bk; pp.ba = ba; pp.br = br; pp.bb0 = bb0; pp.bb1 = bb1;
  pp.g_in = g_in; pp.b_in = b_in; pp.g0 = g0; pp.be0 = be0;
  pp.P = wsp; pp.bcomb = bcomb; pp.bb0adj = bb0adj; pp.bb1adj = bb1adj;
  prep_kern<<<3267, 256, 0, stream>>>(pp);

  float* out = (float*)d_out;
  MegaParams P;
  P.key = key; P.aux = aux; P.res = res; P.role = role;
  P.pWcat = pWcat; P.pWb0 = pWb0; P.pWb1 = pWb1; P.pWad = pWad;
  P.pWw = pWw; P.pWq = pWq;
  P.bcomb = bcomb; P.bb0adj = bb0adj; P.bb1adj = bb1adj;
  P.g1 = g1; P.be1 = be1; P.bad = bad; P.bw = bw; P.bq = bq;
  P.out_logits = out;
  P.out_h = out + (size_t)N_PKT * NCOMP;
  P.out_aux = out + (size_t)N_PKT * (NCOMP + HDIM);
  mega_kern<<<N_PKT / 64, 256, 0, stream>>>(P);
}

// Round 17
// 356.829 us; speedup vs baseline: 2.3778x; 1.2152x over previous
//
#include <hip/hip_runtime.h>
#include <hip/hip_bf16.h>

#define N_PKT 131072
#define KD 128
#define DM 256
#define HDIM 256
#define NCOMP 1024
#define ADIM 64

typedef __attribute__((ext_vector_type(8))) short v8s;
typedef __attribute__((ext_vector_type(4))) float v4f;

__device__ inline unsigned short f2bf(float f) {
  __hip_bfloat16 h = __float2bfloat16(f);
  return *reinterpret_cast<unsigned short*>(&h);
}

__device__ inline float bf2f(unsigned short u) {
  return __uint_as_float(((unsigned)u) << 16);
}

// exact tanh-GELU, 8-op form: x - x / (1 + exp2(x*(c1 + c2*x^2)))
__device__ inline float gelu_f(float x) {
  float x2 = x * x;
  float p = fmaf(x2, 0.10294540f, 2.30208889f);  // 2*0.79788456*log2e*(1, 0.044715)
  float e = __builtin_amdgcn_exp2f(x * p);
  float r = __builtin_amdgcn_rcpf(1.0f + e);
  return x - x * r;
}

// ---------------- one-shot prep ----------------
// Pack layout P[((nt*nKT+kt)*64+l)*8+j] = Wrow[kt*32+(l>>4)*8+j] col[nt*16+(l&15)]
//   Wcat (640x256 = [Wk; Wa; 0.1*Wr], nKT=20)   @ 0       (163840 shorts)
//   Wb0' (256x256, row k scaled by g_in[k])     @ 163840
//   Wb1' (256x256, row k scaled by g0[k])       @ 229376
//   Ww   (256x1024)                             @ 294912
//   Wq   (256x1024)                             @ 557056
//   Wad  (256x64)                               @ 819200  (ends 835584)
struct PrepParams {
  const float *Wk, *Wa, *Wr, *Wb0, *Wb1, *Ww, *Wq, *Wad;
  const float *bk, *ba, *br, *bb0, *bb1;
  const float *g_in, *b_in, *g0, *be0;
  unsigned short* P;
  float* bcomb; float* bb0adj; float* bb1adj;
};

__global__ void prep_kern(PrepParams pp) {
  const int tid = threadIdx.x;
  if (blockIdx.x >= 3264) {
    if (blockIdx.x == 3264) {
      pp.bcomb[tid] = pp.bk[tid] + pp.ba[tid] + 0.1f * pp.br[tid];
    } else {
      // bias adjust: bb0' = bb0 + b_in @ Wb0 ; bb1' = bb1 + beta0 @ Wb1
      const float* vsrc = (blockIdx.x == 3265) ? pp.b_in : pp.be0;
      const float* Wsrc = (blockIdx.x == 3265) ? pp.Wb0 : pp.Wb1;
      const float* badd = (blockIdx.x == 3265) ? pp.bb0 : pp.bb1;
      float* dst = (blockIdx.x == 3265) ? pp.bb0adj : pp.bb1adj;
      float s = badd[tid];
      #pragma unroll 8
      for (int k = 0; k < 256; ++k) s = fmaf(vsrc[k], Wsrc[(long)k * 256 + tid], s);
      dst[tid] = s;
    }
    return;
  }
  long gid = (long)blockIdx.x * 256 + tid;
  int K, Nc; long base; int seg;
  if      (gid < 163840) { K = 640; Nc = 256;  base = 0;      seg = 0; }
  else if (gid < 229376) { K = 256; Nc = 256;  base = 163840; seg = 1; }
  else if (gid < 294912) { K = 256; Nc = 256;  base = 229376; seg = 2; }
  else if (gid < 557056) { K = 256; Nc = 1024; base = 294912; seg = 3; }
  else if (gid < 819200) { K = 256; Nc = 1024; base = 557056; seg = 4; }
  else                   { K = 256; Nc = 64;   base = 819200; seg = 5; }
  long idx = gid - base;
  int j = (int)(idx & 7);
  int l = (int)((idx >> 3) & 63);
  long t = idx >> 9;
  int nKT = K >> 5;
  int kt = (int)(t % nKT), nt = (int)(t / nKT);
  int k = kt * 32 + (l >> 4) * 8 + j;
  int n = nt * 16 + (l & 15);
  float v;
  if (seg == 0) {
    if (k < 128)      v = pp.Wk[(long)k * 256 + n];
    else if (k < 384) v = pp.Wa[(long)(k - 128) * 256 + n];
    else              v = 0.1f * pp.Wr[(long)(k - 384) * 256 + n];
  } else if (seg == 1) v = pp.g_in[k] * pp.Wb0[(long)k * 256 + n];
  else if (seg == 2)   v = pp.g0[k] * pp.Wb1[(long)k * 256 + n];
  else if (seg == 3)   v = pp.Ww[(long)k * Nc + n];
  else if (seg == 4)   v = pp.Wq[(long)k * Nc + n];
  else                 v = pp.Wad[(long)k * Nc + n];
  pp.P[gid] = f2bf(v);
}

// ---------------- shared helpers ----------------
// Stage 64 x COLS f32 rows (in-tile permuted order) into LDS as bf16.
// rows[r] in [0,64): full 512B/1KB contiguous row reads, coalescing preserved.
template<int COLS>
__device__ inline void stage_tile(const float* __restrict__ src, long R0,
                                  const int* __restrict__ rows,
                                  unsigned short (&tile)[64][264], int tid) {
  constexpr int C4 = COLS / 4;
  constexpr int NV = 64 * C4;
  #pragma unroll
  for (int i = 0; i < NV / 256; ++i) {
    int idx = tid + i * 256;
    int r = idx / C4;
    int c4 = idx % C4;
    float4 v = *(reinterpret_cast<const float4*>(src + (R0 + rows[r]) * (long)COLS) + c4);
    unsigned long long pk = (unsigned long long)f2bf(v.x)
                          | ((unsigned long long)f2bf(v.y) << 16)
                          | ((unsigned long long)f2bf(v.z) << 32)
                          | ((unsigned long long)f2bf(v.w) << 48);
    *reinterpret_cast<unsigned long long*>(&tile[r][c4 * 4]) = pk;
  }
}

// acc += tile(64 x 32*NKT) @ W-fragments. W packed with K-tile stride KSTRIDE,
// starting at K-tile KTOFF. Wave's n-tile base nt0.
template<int NKT, int KTOFF, int KSTRIDE>
__device__ inline void gemm_acc(const unsigned short* __restrict__ Wp, int nt0,
                                const unsigned short (&tile)[64][264], int lane,
                                v4f (&acc)[4][4]) {
  const int lr = lane & 15, lg = lane >> 4;
  #pragma unroll
  for (int kt = 0; kt < NKT; ++kt) {
    v8s b[4];
    #pragma unroll
    for (int nf = 0; nf < 4; ++nf)
      b[nf] = *reinterpret_cast<const v8s*>(
          Wp + (((long)(nt0 + nf) * KSTRIDE + KTOFF + kt) * 64 + lane) * 8);
    #pragma unroll
    for (int m = 0; m < 4; ++m) {
      v8s a = *reinterpret_cast<const v8s*>(&tile[m * 16 + lr][kt * 32 + lg * 8]);
      #pragma unroll
      for (int nf = 0; nf < 4; ++nf)
        acc[m][nf] = __builtin_amdgcn_mfma_f32_16x16x32_bf16(a, b[nf], acc[m][nf], 0, 0, 0);
    }
  }
}

__device__ inline void init_acc(v4f (&acc)[4][4], const float* __restrict__ bias,
                                int colbase, int lr) {
  float bv[4];
  #pragma unroll
  for (int nf = 0; nf < 4; ++nf) bv[nf] = bias[colbase + nf * 16 + lr];
  #pragma unroll
  for (int m = 0; m < 4; ++m)
    #pragma unroll
    for (int nf = 0; nf < 4; ++nf)
      acc[m][nf] = (v4f){bv[nf], bv[nf], bv[nf], bv[nf]};
}

// GELU(opt) -> LN over 256 cols. AFFINE==false: write normalized z (affine folded
// into next weights). AFFINE==true: y = z*g+b written to tile.
template<bool GELU, bool AFFINE>
__device__ inline void ln_stage(v4f (&acc)[4][4], int wave, int lane,
                                const float* __restrict__ gamma, const float* __restrict__ beta,
                                unsigned short (&tile)[64][264], float (&stats)[2][4][64]) {
  const int lr = lane & 15, lg = lane >> 4;
  if (GELU) {
    #pragma unroll
    for (int m = 0; m < 4; ++m)
      #pragma unroll
      for (int nf = 0; nf < 4; ++nf)
        #pragma unroll
        for (int r = 0; r < 4; ++r)
          acc[m][nf][r] = gelu_f(acc[m][nf][r]);
  }
  float s[4][4], q[4][4];
  #pragma unroll
  for (int m = 0; m < 4; ++m)
    #pragma unroll
    for (int r = 0; r < 4; ++r) {
      float t = 0.f, t2 = 0.f;
      #pragma unroll
      for (int nf = 0; nf < 4; ++nf) { float v = acc[m][nf][r]; t += v; t2 = fmaf(v, v, t2); }
      s[m][r] = t; q[m][r] = t2;
    }
  #pragma unroll
  for (int off = 1; off < 16; off <<= 1)
    #pragma unroll
    for (int m = 0; m < 4; ++m)
      #pragma unroll
      for (int r = 0; r < 4; ++r) {
        s[m][r] += __shfl_xor(s[m][r], off);
        q[m][r] += __shfl_xor(q[m][r], off);
      }
  if (lr == 0) {
    #pragma unroll
    for (int m = 0; m < 4; ++m)
      #pragma unroll
      for (int r = 0; r < 4; ++r) {
        int row = m * 16 + lg * 4 + r;
        stats[0][wave][row] = s[m][r];
        stats[1][wave][row] = q[m][r];
      }
  }
  __syncthreads();
  float gv[4], bv[4];
  if (AFFINE) {
    #pragma unroll
    for (int nf = 0; nf < 4; ++nf) {
      int c = wave * 64 + nf * 16 + lr;
      gv[nf] = gamma[c]; bv[nf] = beta[c];
    }
  }
  #pragma unroll
  for (int m = 0; m < 4; ++m)
    #pragma unroll
    for (int r = 0; r < 4; ++r) {
      int row = m * 16 + lg * 4 + r;
      float S = stats[0][0][row] + stats[0][1][row] + stats[0][2][row] + stats[0][3][row];
      float Q = stats[1][0][row] + stats[1][1][row] + stats[1][2][row] + stats[1][3][row];
      float mean = S * (1.0f / 256.0f);
      float var  = Q * (1.0f / 256.0f) - mean * mean;
      float rstd = rsqrtf(var + 1e-5f);
      #pragma unroll
      for (int nf = 0; nf < 4; ++nf) {
        int c = wave * 64 + nf * 16 + lr;
        float z = (acc[m][nf][r] - mean) * rstd;
        float y = AFFINE ? fmaf(z, gv[nf], bv[nf]) : z;
        tile[row][c] = f2bf(y);
      }
    }
  __syncthreads();
}

// ---------------- fused kernel: in-tile role sort + backbone + heads ----------------
struct MegaParams {
  const float* key; const float* aux; const float* res; const int* role;
  const unsigned short* pWcat; const unsigned short* pWb0; const unsigned short* pWb1;
  const unsigned short* pWad; const unsigned short* pWw; const unsigned short* pWq;
  const float* bcomb; const float* bb0adj; const float* bb1adj;
  const float* g1; const float* be1; const float* bad;
  const float* bw; const float* bq;
  float* out_logits; float* out_h; float* out_aux;
};

__global__ __launch_bounds__(256, 3) void mega_kern(MegaParams p) {
  __shared__ alignas(16) unsigned short tile[64][264];
  __shared__ float stats[2][4][64];
  __shared__ alignas(16) float stage[4][16][68];   // also aliased as [64][68] for aux
  __shared__ int rows[64];
  __shared__ int nwS;

  const int tid = threadIdx.x;
  const int lane = tid & 63;
  const int wave = tid >> 6;
  const int lr = lane & 15;
  const int lg = lane >> 4;
  const long R0 = (long)blockIdx.x * 64;
  const int nt0 = wave * 4;

  // ---- in-tile role sort: writers to slots [0, nw), others [nw, 64) ----
  if (tid < 64) {
    int w = (p.role[R0 + tid] == 0) ? 1 : 0;
    unsigned long long mw = __ballot(w != 0);
    unsigned long long below = (tid == 0) ? 0ull : (~0ull >> (64 - tid));
    int nw = __popcll(mw);
    int pos = w ? __popcll(mw & below) : nw + __popcll((~mw) & below);
    rows[pos] = tid;
    if (tid == 0) nwS = nw;
  }
  __syncthreads();
  const int nw = nwS;

  v4f acc[4][4];

  // ---- stage 1: [key|aux|res] @ Wcat (K=640, nKT=20: kt 0-3 key, 4-11 aux, 12-19 res) ----
  init_acc(acc, p.bcomb, wave * 64, lr);
  stage_tile<KD>(p.key, R0, rows, tile, tid);
  __syncthreads();
  gemm_acc<4, 0, 20>(p.pWcat, nt0, tile, lane, acc);
  __syncthreads();
  stage_tile<DM>(p.aux, R0, rows, tile, tid);
  __syncthreads();
  gemm_acc<8, 4, 20>(p.pWcat, nt0, tile, lane, acc);
  __syncthreads();
  stage_tile<DM>(p.res, R0, rows, tile, tid);
  __syncthreads();
  gemm_acc<8, 12, 20>(p.pWcat, nt0, tile, lane, acc);
  ln_stage<false, false>(acc, wave, lane, nullptr, nullptr, tile, stats);

  // ---- backbone layer 0 (g_in folded into pWb0, b_in folded into bb0adj) ----
  init_acc(acc, p.bb0adj, wave * 64, lr);
  gemm_acc<8, 0, 8>(p.pWb0, nt0, tile, lane, acc);
  ln_stage<true, false>(acc, wave, lane, nullptr, nullptr, tile, stats);

  // ---- backbone layer 1 (g0 folded into pWb1; last LN keeps affine) ----
  init_acc(acc, p.bb1adj, wave * 64, lr);
  gemm_acc<8, 0, 8>(p.pWb1, nt0, tile, lane, acc);
  ln_stage<true, true>(acc, wave, lane, p.g1, p.be1, tile, stats);

  // ---- coalesced h dump: full 1KB row per wave-instruction (in-tile scatter) ----
  #pragma unroll
  for (int i = 0; i < 16; ++i) {
    int slot = wave * 16 + i;
    unsigned long long t4 = *reinterpret_cast<const unsigned long long*>(&tile[slot][lane * 4]);
    v4f v;
    v[0] = bf2f((unsigned short)(t4 & 0xffff));
    v[1] = bf2f((unsigned short)((t4 >> 16) & 0xffff));
    v[2] = bf2f((unsigned short)((t4 >> 32) & 0xffff));
    v[3] = bf2f((unsigned short)((t4 >> 48) & 0xffff));
    *reinterpret_cast<v4f*>(p.out_h + (R0 + rows[slot]) * HDIM + lane * 4) = v;
  }

  // ---- address head: compute, stage into LDS ([64][68] alias), full-row stores ----
  {
    float (*astage)[68] = reinterpret_cast<float(*)[68]>(&stage[0][0][0]);
    v4f a4[4];
    float bv = p.bad[wave * 16 + lr];
    #pragma unroll
    for (int m = 0; m < 4; ++m) a4[m] = (v4f){bv, bv, bv, bv};
    #pragma unroll
    for (int kt = 0; kt < 8; ++kt) {
      v8s b = *reinterpret_cast<const v8s*>(p.pWad + (((long)wave * 8 + kt) * 64 + lane) * 8);
      #pragma unroll
      for (int m = 0; m < 4; ++m) {
        v8s am = *reinterpret_cast<const v8s*>(&tile[m * 16 + lr][kt * 32 + lg * 8]);
        a4[m] = __builtin_amdgcn_mfma_f32_16x16x32_bf16(am, b, a4[m], 0, 0, 0);
      }
    }
    #pragma unroll
    for (int m = 0; m < 4; ++m)
      #pragma unroll
      for (int r = 0; r < 4; ++r)
        astage[m * 16 + lg * 4 + r][wave * 16 + lr] = a4[m][r];
    __syncthreads();
    #pragma unroll
    for (int k = 0; k < 4; ++k) {
      int idx = tid + k * 256;
      int slot = idx >> 4;
      int c4 = idx & 15;
      v4f v = *reinterpret_cast<const v4f*>(&astage[slot][c4 * 4]);
      *reinterpret_cast<v4f*>(p.out_aux + (R0 + rows[slot]) * ADIM + c4 * 4) = v;
    }
    __syncthreads();   // aux reads of stage done before role heads reuse it
  }

  // ---- role heads: sorted tile => per-m-subtile head skip; full-line stores ----
  const int rr = lane >> 3;   // 0..7
  const int ce = lane & 7;    // 0..7
  #pragma unroll 1
  for (int hsel = 0; hsel < 2; ++hsel) {
    const unsigned short* Wp = hsel == 0 ? p.pWw : p.pWq;
    const float* bias = hsel == 0 ? p.bw : p.bq;
    // m-subtile [m*16, m*16+16) needed for this head? (block-uniform => no divergence)
    bool needm[4];
    #pragma unroll
    for (int m = 0; m < 4; ++m)
      needm[m] = (hsel == 0) ? (m * 16 < nw) : ((m + 1) * 16 > nw);
    #pragma unroll 1
    for (int c = 0; c < 4; ++c) {
      const int nth = wave * 16 + c * 4;
      v4f hacc[4][4];
      #pragma unroll
      for (int nf = 0; nf < 4; ++nf) {
        v4f bv = *reinterpret_cast<const v4f*>(bias + (nth + nf) * 16 + lg * 4);
        #pragma unroll
        for (int m = 0; m < 4; ++m) hacc[m][nf] = bv;
      }
      v8s wcur[4], wnxt[4];
      #pragma unroll
      for (int nf = 0; nf < 4; ++nf)
        wcur[nf] = *reinterpret_cast<const v8s*>(Wp + (((long)(nth + nf) * 8 + 0) * 64 + lane) * 8);
      #pragma unroll
      for (int kt = 0; kt < 8; ++kt) {
        if (kt < 7) {
          #pragma unroll
          for (int nf = 0; nf < 4; ++nf)
            wnxt[nf] = *reinterpret_cast<const v8s*>(Wp + (((long)(nth + nf) * 8 + kt + 1) * 64 + lane) * 8);
        }
        #pragma unroll
        for (int m = 0; m < 4; ++m) {
          if (!needm[m]) continue;
          v8s a = *reinterpret_cast<const v8s*>(&tile[m * 16 + lr][kt * 32 + lg * 8]);
          #pragma unroll
          for (int nf = 0; nf < 4; ++nf)
            hacc[m][nf] = __builtin_amdgcn_mfma_f32_16x16x32_bf16(wcur[nf], a, hacc[m][nf], 0, 0, 0);
        }
        if (kt < 7) {
          #pragma unroll
          for (int nf = 0; nf < 4; ++nf) wcur[nf] = wnxt[nf];
        }
      }
      // epilogue: per-wave LDS transpose -> 128B-aligned full-line stores
      #pragma unroll
      for (int m = 0; m < 4; ++m) {
        if (!needm[m]) continue;
        #pragma unroll
        for (int nf = 0; nf < 4; ++nf)
          *reinterpret_cast<v4f*>(&stage[wave][lr][nf * 16 + lg * 4]) = hacc[m][nf];
        __builtin_amdgcn_sched_barrier(0);
        #pragma unroll
        for (int rh = 0; rh < 2; ++rh) {
          int slot = m * 16 + rh * 8 + rr;
          bool doit = (hsel == 0) ? (slot < nw) : (slot >= nw);
          int ridx = rows[slot];
          #pragma unroll
          for (int ch = 0; ch < 2; ++ch) {
            v4f v = *reinterpret_cast<const v4f*>(&stage[wave][rh * 8 + rr][ch * 32 + ce * 4]);
            if (doit)
              *reinterpret_cast<v4f*>(p.out_logits + (R0 + ridx) * NCOMP
                                      + nth * 16 + ch * 32 + ce * 4) = v;
          }
        }
        __builtin_amdgcn_sched_barrier(0);
      }
    }
  }
}

extern "C" void kernel_launch(void* const* d_in, const int* in_sizes, int n_in,
                              void* d_out, int out_size, void* d_ws, size_t ws_size,
                              hipStream_t stream) {
  const float* key  = (const float*)d_in[0];
  const float* aux  = (const float*)d_in[1];
  const float* res  = (const float*)d_in[2];
  const int*   role = (const int*)d_in[3];
  const float* Wk = (const float*)d_in[4];   const float* bk = (const float*)d_in[5];
  const float* Wa = (const float*)d_in[6];   const float* ba = (const float*)d_in[7];
  const float* Wr = (const float*)d_in[8];   const float* br = (const float*)d_in[9];
  const float* g_in = (const float*)d_in[10]; const float* b_in = (const float*)d_in[11];
  const float* Wb0 = (const float*)d_in[12]; const float* bb0 = (const float*)d_in[13];
  const float* g0 = (const float*)d_in[14];  const float* be0 = (const float*)d_in[15];
  const float* Wb1 = (const float*)d_in[16]; const float* bb1 = (const float*)d_in[17];
  const float* g1 = (const float*)d_in[18];  const float* be1 = (const float*)d_in[19];
  const float* Ww = (const float*)d_in[20];  const float* bw = (const float*)d_in[21];
  const float* Wq = (const float*)d_in[22];  const float* bq = (const float*)d_in[23];
  const float* Wad = (const float*)d_in[24]; const float* bad = (const float*)d_in[25];

  unsigned short* wsp = (unsigned short*)d_ws;
  unsigned short* pWcat = wsp + 0;
  unsigned short* pWb0  = wsp + 163840;
  unsigned short* pWb1  = wsp + 229376;
  unsigned short* pWw   = wsp + 294912;
  unsigned short* pWq   = wsp + 557056;
  unsigned short* pWad  = wsp + 819200;
  char* wsb = (char*)d_ws;
  float* bcomb  = (float*)(wsb + 1671168);
  float* bb0adj = (float*)(wsb + 1672192);
  float* bb1adj = (float*)(wsb + 1673216);

  PrepParams pp;
  pp.Wk = Wk; pp.Wa = Wa; pp.Wr = Wr; pp.Wb0 = Wb0; pp.Wb1 = Wb1;
  pp.Ww = Ww; pp.Wq = Wq; pp.Wad = Wad;
  pp.bk = bk; pp.ba = ba; pp.br = br; pp.bb0 = bb0; pp.bb1 = bb1;
  pp.g_in = g_in; pp.b_in = b_in; pp.g0 = g0; pp.be0 = be0;
  pp.P = wsp; pp.bcomb = bcomb; pp.bb0adj = bb0adj; pp.bb1adj = bb1adj;
  prep_kern<<<3267, 256, 0, stream>>>(pp);

  float* out = (float*)d_out;
  MegaParams P;
  P.key = key; P.aux = aux; P.res = res; P.role = role;
  P.pWcat = pWcat; P.pWb0 = pWb0; P.pWb1 = pWb1; P.pWad = pWad;
  P.pWw = pWw; P.pWq = pWq;
  P.bcomb = bcomb; P.bb0adj = bb0adj; P.bb1adj = bb1adj;
  P.g1 = g1; P.be1 = be1; P.bad = bad; P.bw = bw; P.bq = bq;
  P.out_logits = out;
  P.out_h = out + (size_t)N_PKT * NCOMP;
  P.out_aux = out + (size_t)N_PKT * (NCOMP + HDIM);
  mega_kern<<<N_PKT / 64, 256, 0, stream>>>(P);
}